// Round 14
// baseline (301.255 us; speedup 1.0000x reference)
//
#include <hip/hip_runtime.h>

#define DEV static __device__ __forceinline__

typedef __attribute__((ext_vector_type(8))) short bf16x8;
typedef __attribute__((ext_vector_type(4))) float f32x4;

#define MFMA(a, b, c) __builtin_amdgcn_mfma_f32_16x16x32_bf16(a, b, c, 0, 0, 0)

DEV float bf2f(unsigned short h) { return __uint_as_float(((unsigned)h) << 16); }
DEV unsigned short f2bf(float f) {
  unsigned u = __float_as_uint(f);
  u += 0x7fffu + ((u >> 16) & 1u);
  return (unsigned short)(u >> 16);
}
DEV bf16x8 ld8(const unsigned short* p) { return *(const bf16x8*)p; }

DEV float dotg64(const float* x, const float* wrow) {
  const float4* wp = (const float4*)wrow;
  float a0 = 0.f, a1 = 0.f;
  #pragma unroll
  for (int c = 0; c < 8; ++c) {
    float4 u = wp[2*c], v = wp[2*c + 1];
    a0 = fmaf(u.x, x[8*c+0], a0); a0 = fmaf(u.y, x[8*c+1], a0);
    a0 = fmaf(u.z, x[8*c+2], a0); a0 = fmaf(u.w, x[8*c+3], a0);
    a1 = fmaf(v.x, x[8*c+4], a1); a1 = fmaf(v.y, x[8*c+5], a1);
    a1 = fmaf(v.z, x[8*c+6], a1); a1 = fmaf(v.w, x[8*c+7], a1);
  }
  return a0 + a1;
}
DEV float wred64(float v) {
  #pragma unroll
  for (int o = 32; o > 0; o >>= 1) v += __shfl_xor(v, o, 64);
  return v;
}

// d_ws layout (ushort element offsets): weights as bf16 hi/lo pairs.
// Fused composites: C0 = mW0@oW0, C1 = mW1@oW1, S = mW0+mW1 (hi/lo each),
// b' = mb + mW0@ob0 + mW1@ob1.
#define XW_HI 0        // 4*2*128*64 = 65536
#define XW_LO 65536
#define CW 131072      // per layer 24576: C0H,C0L,C1H,C1L,SH,SL (each 4096)
#define AI_HI 262144
#define AI_LO 274432
#define SC_OFF 286720  // f32: 8*256 gate-poly coefs
#define BP_OFF 290816  // f32: 4*64 fused bias b'

// bf16 tiles: 48 rows x 64 cols (40 real tokens + 8 pad), stride 64, XOR
// swizzle elem(row,d) = (row<<6) + (d ^ ((row&7)<<3)). Pad rows of s_xnb are
// zeroed once; pad outputs in bG/bB are finite garbage, never consumed
// (row>=40 writes guarded; garbage A-frag rows only feed garbage C rows).

__global__ void prep_kernel(const float* __restrict__ xW, const float* __restrict__ oW,
                            const float* __restrict__ ob, const float* __restrict__ mW,
                            const float* __restrict__ mb, const float* __restrict__ aiW,
                            const float* __restrict__ Ap, unsigned short* __restrict__ wsb) {
  const int gid = blockIdx.x * blockDim.x + threadIdx.x;
  const int stride = gridDim.x * blockDim.x;
  for (int i = gid; i < 65536; i += stride) {
    float x = xW[i]; unsigned short h = f2bf(x);
    wsb[XW_HI + i] = h; wsb[XW_LO + i] = f2bf(x - bf2f(h));
  }
  for (int i = gid; i < 32768; i += stride) {
    int L = i >> 13, rem = i & 8191;
    int dir = rem >> 12, n = (rem >> 6) & 63, d = rem & 63;
    const float* mrow = mW + L*8192 + n*128 + dir*64;
    const float* ocol = oW + L*8192 + dir*4096 + d;
    float acc = 0.f;
    #pragma unroll 8
    for (int j = 0; j < 64; ++j) acc = fmaf(mrow[j], ocol[j*64], acc);
    unsigned short h = f2bf(acc);
    int base = CW + L*24576 + dir*8192;
    wsb[base + n*64 + d] = h;
    wsb[base + 4096 + n*64 + d] = f2bf(acc - bf2f(h));
  }
  for (int i = gid; i < 16384; i += stride) {
    int L = i >> 12, n = (i >> 6) & 63, j = i & 63;
    float v = mW[L*8192 + n*128 + j] + mW[L*8192 + n*128 + 64 + j];
    unsigned short h = f2bf(v);
    int base = CW + L*24576 + 16384;
    wsb[base + n*64 + j] = h;
    wsb[base + 4096 + n*64 + j] = f2bf(v - bf2f(h));
  }
  {
    float* bp = (float*)(wsb + BP_OFF);
    for (int i = gid; i < 256; i += stride) {
      int L = i >> 6, n = i & 63;
      const float* mrow = mW + L*8192 + n*128;
      float acc = mb[L*64 + n];
      #pragma unroll 8
      for (int j = 0; j < 64; ++j) acc = fmaf(ob[(2*L)*64 + j], mrow[j], acc);
      #pragma unroll 8
      for (int j = 0; j < 64; ++j) acc = fmaf(ob[(2*L+1)*64 + j], mrow[64 + j], acc);
      bp[i] = acc;
    }
  }
  for (int i = gid; i < 12288; i += stride) {
    float x = aiW[i]; unsigned short h = f2bf(x);
    wsb[AI_HI + i] = h; wsb[AI_LO + i] = f2bf(x - bf2f(h));
  }
  float* sc = (float*)(wsb + SC_OFF);
  for (int i = gid; i < 512; i += stride) {
    int pi = i >> 6, d = i & 63;
    const float* a = Ap + (size_t)i * 16;
    float s1 = 0, s2 = 0, s3 = 0, s4 = 0;
    #pragma unroll
    for (int n = 0; n < 16; ++n) {
      float z = a[n]; float z2 = z * z;
      s1 += z; s2 += z2; s3 += z2 * z; s4 += z2 * z2;
    }
    sc[pi*256 + d]       = s1;
    sc[pi*256 + 64 + d]  = s2 * 0.5f;
    sc[pi*256 + 128 + d] = s3 * (1.f/6.f);
    sc[pi*256 + 192 + d] = s4 * (1.f/24.f);
  }
}

// R14 = R13's per-row pipeline at 1 ROW PER BLOCK: 256 thr, LDS 40,960 B
// exactly -> FOUR independent blocks/CU (R3 measured 43% occupancy at this
// exact LDS size, proving 4x40,960 co-residency), 16 waves/CU, grid 1024 =
// single generation. R13 showed independent-block overlap pays (+5% at 2
// blocks) where same-block TLP failed (R11); this doubles the independent
// count. (256,2) bounds keep the 256-reg budget (R2's spill trap avoided;
// this pipeline compiles at 88 regs). Per-row math identical to R13.
// Falsifiers: occ ~25-32% -> 4th block blocked, revert; occ ~45% + flat dur
// -> TLP exhausted, R13 is the structural floor.
__global__ __launch_bounds__(256, 2)
void Mamba4CTRV17_kernel(
    const float* __restrict__ dense_x, const float* __restrict__ dense_W,
    const float* __restrict__ dense_b, const float* __restrict__ tbl,
    const float* __restrict__ cls, const float* __restrict__ ng,
    const float* __restrict__ nb, const float* __restrict__ xb,
    const float* __restrict__ Dp, const float* __restrict__ ob,
    const float* __restrict__ mb, const float* __restrict__ aib,
    const float* __restrict__ aoW, const float* __restrict__ aob,
    const float* __restrict__ w1, const float* __restrict__ b1,
    const float* __restrict__ w2, const float* __restrict__ b2,
    const float* __restrict__ w3, const float* __restrict__ b3,
    const int* __restrict__ sidx, const unsigned short* __restrict__ wsb,
    float* __restrict__ out) {
  __shared__ __align__(16) unsigned char smem[40960];
  float*          s_seq  = (float*)smem;                     // 40x64 f32 spine (10240)
  unsigned short* s_xnb  = (unsigned short*)(smem + 10240);  // 48x64 bf16 xn / final seq (6144)
  unsigned short* bG0    = (unsigned short*)(smem + 16384);  // gate0->scanout0 ; f32 scratch g0f
  unsigned short* bG1    = (unsigned short*)(smem + 22528);  // gate1->scanout1 ; f32 scratch g1f
  unsigned short* bB0    = (unsigned short*)(smem + 28672);  // Bm0 -> residual bf16 (in-scan) ; tail: K
  unsigned short* bB1    = (unsigned short*)(smem + 34816);  // Bm1 ; tail: V
  float* g0f = (float*)bG0;  // tail: {probs320, q@320..383, seq0@384, c@448} ; phase0: {dx13, idx26}
  float* g1f = (float*)bG1;  // tail: {aopart256, ao@256, mlp1@320, mlp2@448}
  const float* scf = (const float*)(wsb + SC_OFF);
  const float* bpf = (const float*)(wsb + BP_OFF);

  const int tid = threadIdx.x, b = blockIdx.x;
  const int lane = tid & 63, wv = tid >> 6;  // wv 0..3
  const int arow = lane & 15;
  const int aq = (lane >> 4) * 8;
  const int rq = (lane >> 4) * 4;
  const int rq7 = rq & 7;
  const int swA = (arow & 7) << 3;
  const int aqs0 = aq ^ swA, aqs1 = (aq + 32) ^ swA;

  // ---------------- Phase 0: build seq (40 tokens) ----------------
  {
    float* s_dx = g0f;                 // 13 f32
    int* s_idx = (int*)(g0f + 16);     // 26 ints
    if (tid < 13) s_dx[tid] = dense_x[b*13 + tid];
    if (tid >= 64 && tid < 90) {
      int si = tid - 64;
      int v = sidx[b*26 + si];
      v = v < 0 ? 0 : (v > 10000 ? 10000 : v);
      s_idx[si] = v;
    }
    // zero s_xnb pad rows 40..47 (512 u16 = 256 u32) -- stays zero all layers
    ((unsigned int*)(s_xnb + 2560))[tid] = 0u;
    __syncthreads();
    if (tid < 64) s_seq[tid] = cls[tid];
    {
      float x[13];
      #pragma unroll
      for (int k = 0; k < 13; ++k) x[k] = s_dx[k];
      for (int j = tid; j < 832; j += 256) {
        float acc = dense_b[j];
        #pragma unroll
        for (int k = 0; k < 13; ++k) acc = fmaf(x[k], dense_W[j*13 + k], acc);
        s_seq[(1 + (j >> 6))*64 + (j & 63)] = acc;
      }
    }
    for (int e = tid; e < 416; e += 256) {
      int s = e >> 4, c = e & 15;
      const float4* row = (const float4*)(tbl + ((size_t)(s*10001 + s_idx[s]))*64);
      ((float4*)&s_seq[(14 + s)*64])[c] = row[c];
    }
  }
  __syncthreads();

  // ---------------- 4 bidirectional mamba layers ----------------
  for (int L = 0; L < 4; ++L) {
    const int pi0 = 2*L, pi1 = 2*L + 1;

    // LN 4-wide: 40 tokens = 3 sweeps x (4 waves x 4 groups), guard t<40.
    {
      const int g = lane >> 4, dl = lane & 15;
      const int dbase = 4 * ((dl + 4*g) & 15);
      const float4 ngv = *(const float4*)&ng[pi0*64 + dbase];
      const float4 nbv = *(const float4*)&nb[pi0*64 + dbase];
      #pragma unroll 1
      for (int sweep = 0; sweep < 3; ++sweep) {
        int t = sweep*16 + wv*4 + g;  // 0..47, group-uniform guard
        if (t < 40) {
          const float4 xv = *(const float4*)&s_seq[t*64 + dbase];
          float s = (xv.x + xv.y) + (xv.z + xv.w);
          float q = fmaf(xv.x, xv.x, fmaf(xv.y, xv.y, fmaf(xv.z, xv.z, xv.w*xv.w)));
          #pragma unroll
          for (int o = 8; o > 0; o >>= 1) { s += __shfl_xor(s, o, 64); q += __shfl_xor(q, o, 64); }
          float mean = s * (1.f/64.f);
          float var = q * (1.f/64.f) - mean*mean;
          float rs = rsqrtf(var + 1e-5f);
          unsigned short h0 = f2bf(fmaf((xv.x - mean)*rs, ngv.x, nbv.x));
          unsigned short h1 = f2bf(fmaf((xv.y - mean)*rs, ngv.y, nbv.y));
          unsigned short h2 = f2bf(fmaf((xv.z - mean)*rs, ngv.z, nbv.z));
          unsigned short h3 = f2bf(fmaf((xv.w - mean)*rs, ngv.w, nbv.w));
          int o2 = (t << 6) + (dbase ^ ((t & 7) << 3));
          unsigned lo = (unsigned)h0 | ((unsigned)h1 << 16);
          unsigned hi = (unsigned)h2 | ((unsigned)h3 << 16);
          *(uint2*)&s_xnb[o2] = make_uint2(lo, hi);
        }
      }
    }
    __syncthreads();

    // xproj both dirs fused: 2 passes (delta / Bm), wave w -> col-tile
    // (w + cti*4), 3 mt each (48-row tiles; pad outputs garbage, unconsumed).
    {
      #pragma unroll 1
      for (int cti = 0; cti < 2; ++cti) {
        const int j = (wv + cti*4)*16 + arow;  // 0..127
        const unsigned short* Wh0 = wsb + XW_HI + pi0*8192 + j*64;
        const unsigned short* Wl0 = wsb + XW_LO + pi0*8192 + j*64;
        const unsigned short* Wh1 = wsb + XW_HI + pi1*8192 + j*64;
        const unsigned short* Wl1 = wsb + XW_LO + pi1*8192 + j*64;
        bf16x8 bh00 = ld8(Wh0 + aq), bh01 = ld8(Wh0 + 32 + aq);
        bf16x8 bl00 = ld8(Wl0 + aq), bl01 = ld8(Wl0 + 32 + aq);
        bf16x8 bh10 = ld8(Wh1 + aq), bh11 = ld8(Wh1 + 32 + aq);
        bf16x8 bl10 = ld8(Wl1 + aq), bl11 = ld8(Wl1 + 32 + aq);
        const float bj0 = xb[pi0*128 + j], bj1 = xb[pi1*128 + j];
        const bool isDelta = (cti == 0);  // uniform per pass
        float c10=0,c20=0,c30=0,c40=0,c11=0,c21=0,c31=0,c41=0;
        if (isDelta) {
          c10=scf[pi0*256+j]; c20=scf[pi0*256+64+j]; c30=scf[pi0*256+128+j]; c40=scf[pi0*256+192+j];
          c11=scf[pi1*256+j]; c21=scf[pi1*256+64+j]; c31=scf[pi1*256+128+j]; c41=scf[pi1*256+192+j];
        }
        #pragma unroll 1
        for (int mt = 0; mt < 3; ++mt) {
          const unsigned short* A = s_xnb + ((mt*16 + arow) << 6);
          bf16x8 ah0 = ld8(A + aqs0), ah1 = ld8(A + aqs1);
          f32x4 a0 = {0,0,0,0}, a1 = {0,0,0,0};
          a0 = MFMA(ah0, bh00, a0); a0 = MFMA(ah0, bl00, a0);
          a0 = MFMA(ah1, bh01, a0); a0 = MFMA(ah1, bl01, a0);
          a1 = MFMA(ah0, bh10, a1); a1 = MFMA(ah0, bl10, a1);
          a1 = MFMA(ah1, bh11, a1); a1 = MFMA(ah1, bl11, a1);
          const int rbase = mt*16 + rq;
          #pragma unroll
          for (int r = 0; r < 4; ++r) {
            int row = rbase + r;  // 0..47 (pad rows garbage, never consumed)
            int swr = (rq7 + r) << 3;
            float x0v = a0[r] + bj0, x1v = a1[r] + bj1;
            if (isDelta) {
              float sp0 = fmaxf(x0v, 0.f) + __logf(1.f + __expf(-fabsf(x0v)));
              float sp1 = fmaxf(x1v, 0.f) + __logf(1.f + __expf(-fabsf(x1v)));
              int o = (row << 6) + (j ^ swr);
              bG0[o] = f2bf(sp0 * fmaf(sp0, fmaf(sp0, fmaf(sp0, c40, c30), c20), c10));
              bG1[o] = f2bf(sp1 * fmaf(sp1, fmaf(sp1, fmaf(sp1, c41, c31), c21), c11));
            } else {
              int o = (row << 6) + ((j - 64) ^ swr);
              bB0[o] = f2bf(x0v);
              bB1[o] = f2bf(x1v);
            }
          }
        }
      }
    }
    __syncthreads();

    // Scan: wave0 = dir0 (d = lane), wave1 = dir1; 40 scalar steps.
    // dir-0 wave overwrites consumed Bm0 with the bf16 residual (s_seq),
    // building the swizzled residual tile for the fused phase for free.
    if (tid < 128) {
      const int d = lane, dir = wv;  // wave-uniform dir
      unsigned short* bmb = dir ? bB1 : bB0;
      unsigned short* gb = dir ? bG1 : bG0;
      const float dpd = Dp[(pi0 + dir)*64 + d];
      float run = 0.f;
      #pragma unroll
      for (int k = 0; k < 40; ++k) {
        int t = dir ? (39 - k) : k;
        int o = (t << 6) + (d ^ ((t & 7) << 3));
        float xn = bf2f(s_xnb[o]);
        run = fmaf(xn, bf2f(bmb[o]), run);
        float gate = 16.f + bf2f(gb[o]);
        gb[o] = f2bf(fmaf(run, gate, xn * dpd));
        if (dir == 0) bmb[o] = f2bf(s_seq[t*64 + d]);  // wave-uniform branch
      }
    }
    __syncthreads();

    // FUSED out+merge: seq_new = g0@C0^T + g1@C1^T + res@S^T + b'
    // (res tile = bB0). wave w -> col-tile w, 3 mt; writes guarded row<40.
    {
      const int n0 = wv*16 + arow;  // 0..63
      const unsigned short* cbase = wsb + CW + L*24576;
      const unsigned short* C0H = cbase + n0*64;
      const unsigned short* C0L = cbase + 4096 + n0*64;
      const unsigned short* C1H = cbase + 8192 + n0*64;
      const unsigned short* C1L = cbase + 12288 + n0*64;
      const unsigned short* SH  = cbase + 16384 + n0*64;
      const unsigned short* SL  = cbase + 20480 + n0*64;
      bf16x8 c0h0 = ld8(C0H + aq), c0h1 = ld8(C0H + 32 + aq);
      bf16x8 c0l0 = ld8(C0L + aq), c0l1 = ld8(C0L + 32 + aq);
      bf16x8 c1h0 = ld8(C1H + aq), c1h1 = ld8(C1H + 32 + aq);
      bf16x8 c1l0 = ld8(C1L + aq), c1l1 = ld8(C1L + 32 + aq);
      bf16x8 sh0 = ld8(SH + aq), sh1 = ld8(SH + 32 + aq);
      bf16x8 sl0 = ld8(SL + aq), sl1 = ld8(SL + 32 + aq);
      const float bom = bpf[L*64 + n0];
      #pragma unroll 1
      for (int mt = 0; mt < 3; ++mt) {
        const unsigned short* A0 = bG0 + ((mt*16 + arow) << 6);
        const unsigned short* A1 = bG1 + ((mt*16 + arow) << 6);
        const unsigned short* AR = bB0 + ((mt*16 + arow) << 6);
        bf16x8 g00 = ld8(A0 + aqs0), g01 = ld8(A0 + aqs1);
        bf16x8 g10 = ld8(A1 + aqs0), g11 = ld8(A1 + aqs1);
        bf16x8 r0 = ld8(AR + aqs0), r1 = ld8(AR + aqs1);
        f32x4 a0 = {0,0,0,0}, a1 = {0,0,0,0}, a2 = {0,0,0,0};
        a0 = MFMA(g00, c0h0, a0); a0 = MFMA(g00, c0l0, a0);
        a0 = MFMA(g01, c0h1, a0); a0 = MFMA(g01, c0l1, a0);
        a1 = MFMA(g10, c1h0, a1); a1 = MFMA(g10, c1l0, a1);
        a1 = MFMA(g11, c1h1, a1); a1 = MFMA(g11, c1l1, a1);
        a2 = MFMA(r0, sh0, a2); a2 = MFMA(r0, sl0, a2);
        a2 = MFMA(r1, sh1, a2); a2 = MFMA(r1, sl1, a2);
        const int rbase = mt*16 + rq;
        #pragma unroll
        for (int r = 0; r < 4; ++r) {
          int row = rbase + r;
          if (row < 40) {
            float v = a0[r] + a1[r] + a2[r] + bom;
            s_seq[row*64 + n0] = v;
            if (L == 3) s_xnb[(row << 6) + (n0 ^ ((rq7 + r) << 3))] = f2bf(v);
          }
        }
      }
    }
    __syncthreads();
  }

  // ---------------- Attention tail ----------------
  // QKV: 28 units (K/V: 8 ct x 3 mt = 24; Q: 4 ct x mt0 = 4) over 4 waves = 7 each
  {
    #pragma unroll 1
    for (int i = 0; i < 7; ++i) {
      const int u = wv + 4*i;  // 0..27
      int j, mtk;
      if (u < 24) { j = 64 + (u & 7)*16 + arow; mtk = u >> 3; }
      else { int qi = u - 24; j = qi*16 + arow; mtk = 0; }
      const unsigned short* Wh = wsb + AI_HI + j*64;
      const unsigned short* Wl = wsb + AI_LO + j*64;
      bf16x8 bh0 = ld8(Wh + aq), bh1 = ld8(Wh + 32 + aq);
      bf16x8 bl0 = ld8(Wl + aq), bl1 = ld8(Wl + 32 + aq);
      const float bj = aib[j];
      const unsigned short* A = s_xnb + ((mtk*16 + arow) << 6);
      bf16x8 ah0 = ld8(A + aqs0), ah1 = ld8(A + aqs1);
      f32x4 a0 = {0,0,0,0};
      a0 = MFMA(ah0, bh0, a0); a0 = MFMA(ah0, bl0, a0);
      a0 = MFMA(ah1, bh1, a0); a0 = MFMA(ah1, bl1, a0);
      const int rbase = mtk*16 + rq;
      #pragma unroll
      for (int r = 0; r < 4; ++r) {
        int row = rbase + r;
        int swr = (rq7 + r) << 3;
        float val = a0[r] + bj;
        if (u < 24) {  // K/V; pad rows 40..47 written but never read
          if (j < 128) bB0[(row << 6) + ((j - 64) ^ swr)] = f2bf(val);   // K
          else         bB1[(row << 6) + ((j - 128) ^ swr)] = f2bf(val);  // V
        } else {
          if (row == 0) g0f[320 + j] = val;  // q vector
        }
      }
    }
    if (tid < 64) g0f[384 + tid] = s_seq[tid];  // seq token 0
  }
  __syncthreads();

  // logits: 8 heads x 40 keys = 320
  for (int e = tid; e < 320; e += 256) {
    int h = e / 40, kk = e - h*40;
    int kbase = (kk << 6) + ((h*8) ^ ((kk & 7) << 3));  // h*8 mult of 8: +i stays in chunk
    float acc = 0.f;
    #pragma unroll
    for (int i = 0; i < 8; ++i)
      acc += g0f[320 + h*8 + i] * bf2f(bB0[kbase + i]);
    g0f[e] = acc * 0.35355339059327373f;
  }
  __syncthreads();

  // softmax: 8 heads over 4 waves, 32 lanes per head (40 keys = 32+8)
  {
    const int hh = wv*2 + (lane >> 5), jl = lane & 31;
    float* pr = g0f + hh*40;
    float a = pr[jl];
    float bv = (jl < 8) ? pr[32 + jl] : -1e30f;
    float m = fmaxf(a, bv);
    #pragma unroll
    for (int o = 16; o > 0; o >>= 1) m = fmaxf(m, __shfl_xor(m, o, 32));
    float pa = __expf(a - m), pb = (jl < 8) ? __expf(bv - m) : 0.f;
    float s = pa + pb;
    #pragma unroll
    for (int o = 16; o > 0; o >>= 1) s += __shfl_xor(s, o, 32);
    float inv = 1.f / s;
    pr[jl] = pa * inv;
    if (jl < 8) pr[32 + jl] = pb * inv;
  }
  __syncthreads();

  // ao partials: 4 quarters x 64 d = 256 exactly
  {
    const int d = tid & 63, qrt = tid >> 6, hh = d >> 3;
    float acc = 0.f;
    #pragma unroll
    for (int k = qrt*10; k < qrt*10 + 10; ++k) {
      int o = (k << 6) + (d ^ ((k & 7) << 3));
      acc += g0f[hh*40 + k] * bf2f(bB1[o]);
    }
    g1f[qrt*64 + d] = acc;
  }
  __syncthreads();
  if (tid < 64) {
    g1f[256 + tid] = g1f[tid] + g1f[64 + tid] + g1f[128 + tid] + g1f[192 + tid];
  }
  __syncthreads();

  // c = seq0 + ao @ aoW.T + aob
  if (tid < 64) {
    g0f[448 + tid] = g0f[384 + tid] + aob[tid]
                   + dotg64(&g1f[256], aoW + (size_t)tid*64);
  }
  __syncthreads();

  // MLP1
  if (tid < 128) {
    g1f[320 + tid] = fmaxf(b1[tid] + dotg64(&g0f[448], w1 + (size_t)tid*64), 0.f);
  }
  __syncthreads();

  // MLP2
  if (tid < 64) {
    float acc = dotg64(&g1f[320], w2 + (size_t)tid*128)
              + dotg64(&g1f[384], w2 + (size_t)tid*128 + 64);
    g1f[448 + tid] = fmaxf(acc + b2[tid], 0.f);
  }
  __syncthreads();

  if (tid < 64) {
    float v = g1f[448 + lane] * w3[lane];
    v = wred64(v);
    if (lane == 0) out[b] = v + b3[0];
  }
}

extern "C" void kernel_launch(void* const* d_in, const int* in_sizes, int n_in,
                              void* d_out, int out_size, void* d_ws, size_t ws_size,
                              hipStream_t stream) {
  (void)n_in; (void)ws_size; (void)out_size;
  const float* dense_x = (const float*)d_in[0];
  const float* dense_W = (const float*)d_in[1];
  const float* dense_b = (const float*)d_in[2];
  const float* tbl     = (const float*)d_in[3];
  const float* cls     = (const float*)d_in[4];
  const float* ng      = (const float*)d_in[5];
  const float* nb      = (const float*)d_in[6];
  const float* xW      = (const float*)d_in[7];
  const float* xb      = (const float*)d_in[8];
  const float* Ap      = (const float*)d_in[9];
  const float* Dp      = (const float*)d_in[10];
  const float* oW      = (const float*)d_in[11];
  const float* ob      = (const float*)d_in[12];
  const float* mW      = (const float*)d_in[13];
  const float* mb      = (const float*)d_in[14];
  const float* aiW     = (const float*)d_in[15];
  const float* aib     = (const float*)d_in[16];
  const float* aoW     = (const float*)d_in[17];
  const float* aob     = (const float*)d_in[18];
  const float* w1      = (const float*)d_in[19];
  const float* b1      = (const float*)d_in[20];
  const float* w2      = (const float*)d_in[21];
  const float* b2      = (const float*)d_in[22];
  const float* w3      = (const float*)d_in[23];
  const float* b3      = (const float*)d_in[24];
  const int*   sidx    = (const int*)d_in[25];
  float* out = (float*)d_out;
  unsigned short* wsb = (unsigned short*)d_ws;

  hipLaunchKernelGGL(prep_kernel, dim3(256), dim3(256), 0, stream,
                     xW, oW, ob, mW, mb, aiW, Ap, wsb);

  const int B = in_sizes[0] / 13;  // 1024
  hipLaunchKernelGGL(Mamba4CTRV17_kernel, dim3(B), dim3(256), 0, stream,
                     dense_x, dense_W, dense_b, tbl, cls, ng, nb, xb, Dp, ob, mb,
                     aib, aoW, aob, w1, b1, w2, b2, w3, b3, sidx, wsb, out);
}

// Round 15
// 250.190 us; speedup vs baseline: 1.2041x; 1.2041x over previous
//
#include <hip/hip_runtime.h>

#define DEV static __device__ __forceinline__

typedef __attribute__((ext_vector_type(8))) short bf16x8;
typedef __attribute__((ext_vector_type(4))) float f32x4;

#define MFMA(a, b, c) __builtin_amdgcn_mfma_f32_16x16x32_bf16(a, b, c, 0, 0, 0)

DEV float bf2f(unsigned short h) { return __uint_as_float(((unsigned)h) << 16); }
DEV unsigned short f2bf(float f) {
  unsigned u = __float_as_uint(f);
  u += 0x7fffu + ((u >> 16) & 1u);
  return (unsigned short)(u >> 16);
}
DEV bf16x8 ld8(const unsigned short* p) { return *(const bf16x8*)p; }

DEV float dotg64(const float* x, const float* wrow) {
  const float4* wp = (const float4*)wrow;
  float a0 = 0.f, a1 = 0.f;
  #pragma unroll
  for (int c = 0; c < 8; ++c) {
    float4 u = wp[2*c], v = wp[2*c + 1];
    a0 = fmaf(u.x, x[8*c+0], a0); a0 = fmaf(u.y, x[8*c+1], a0);
    a0 = fmaf(u.z, x[8*c+2], a0); a0 = fmaf(u.w, x[8*c+3], a0);
    a1 = fmaf(v.x, x[8*c+4], a1); a1 = fmaf(v.y, x[8*c+5], a1);
    a1 = fmaf(v.z, x[8*c+6], a1); a1 = fmaf(v.w, x[8*c+7], a1);
  }
  return a0 + a1;
}
DEV float wred64(float v) {
  #pragma unroll
  for (int o = 32; o > 0; o >>= 1) v += __shfl_xor(v, o, 64);
  return v;
}

// d_ws layout (ushort element offsets): weights as bf16 hi/lo pairs.
// Fused composites: C0 = mW0@oW0, C1 = mW1@oW1, S = mW0+mW1 (hi/lo each),
// b' = mb + mW0@ob0 + mW1@ob1.
#define XW_HI 0        // 4*2*128*64 = 65536
#define XW_LO 65536
#define CW 131072      // per layer 24576: C0H,C0L,C1H,C1L,SH,SL (each 4096)
#define AI_HI 262144
#define AI_LO 274432
#define SC_OFF 286720  // f32: 8*256 gate-poly coefs
#define BP_OFF 290816  // f32: 4*64 fused bias b'

// bf16 tiles: 48 rows x 64 cols (40 real tokens + 8 pad), stride 64, XOR
// swizzle elem(row,d) = (row<<6) + (d ^ ((row&7)<<3)). Pad rows of s_xnb are
// zeroed once; pad outputs in bG/bB are finite garbage, never consumed
// (row>=40 writes guarded; garbage A-frag rows only feed garbage C rows).

__global__ void prep_kernel(const float* __restrict__ xW, const float* __restrict__ oW,
                            const float* __restrict__ ob, const float* __restrict__ mW,
                            const float* __restrict__ mb, const float* __restrict__ aiW,
                            const float* __restrict__ Ap, unsigned short* __restrict__ wsb) {
  const int gid = blockIdx.x * blockDim.x + threadIdx.x;
  const int stride = gridDim.x * blockDim.x;
  for (int i = gid; i < 65536; i += stride) {
    float x = xW[i]; unsigned short h = f2bf(x);
    wsb[XW_HI + i] = h; wsb[XW_LO + i] = f2bf(x - bf2f(h));
  }
  for (int i = gid; i < 32768; i += stride) {
    int L = i >> 13, rem = i & 8191;
    int dir = rem >> 12, n = (rem >> 6) & 63, d = rem & 63;
    const float* mrow = mW + L*8192 + n*128 + dir*64;
    const float* ocol = oW + L*8192 + dir*4096 + d;
    float acc = 0.f;
    #pragma unroll 8
    for (int j = 0; j < 64; ++j) acc = fmaf(mrow[j], ocol[j*64], acc);
    unsigned short h = f2bf(acc);
    int base = CW + L*24576 + dir*8192;
    wsb[base + n*64 + d] = h;
    wsb[base + 4096 + n*64 + d] = f2bf(acc - bf2f(h));
  }
  for (int i = gid; i < 16384; i += stride) {
    int L = i >> 12, n = (i >> 6) & 63, j = i & 63;
    float v = mW[L*8192 + n*128 + j] + mW[L*8192 + n*128 + 64 + j];
    unsigned short h = f2bf(v);
    int base = CW + L*24576 + 16384;
    wsb[base + n*64 + j] = h;
    wsb[base + 4096 + n*64 + j] = f2bf(v - bf2f(h));
  }
  {
    float* bp = (float*)(wsb + BP_OFF);
    for (int i = gid; i < 256; i += stride) {
      int L = i >> 6, n = i & 63;
      const float* mrow = mW + L*8192 + n*128;
      float acc = mb[L*64 + n];
      #pragma unroll 8
      for (int j = 0; j < 64; ++j) acc = fmaf(ob[(2*L)*64 + j], mrow[j], acc);
      #pragma unroll 8
      for (int j = 0; j < 64; ++j) acc = fmaf(ob[(2*L+1)*64 + j], mrow[64 + j], acc);
      bp[i] = acc;
    }
  }
  for (int i = gid; i < 12288; i += stride) {
    float x = aiW[i]; unsigned short h = f2bf(x);
    wsb[AI_HI + i] = h; wsb[AI_LO + i] = f2bf(x - bf2f(h));
  }
  float* sc = (float*)(wsb + SC_OFF);
  for (int i = gid; i < 512; i += stride) {
    int pi = i >> 6, d = i & 63;
    const float* a = Ap + (size_t)i * 16;
    float s1 = 0, s2 = 0, s3 = 0, s4 = 0;
    #pragma unroll
    for (int n = 0; n < 16; ++n) {
      float z = a[n]; float z2 = z * z;
      s1 += z; s2 += z2; s3 += z2 * z; s4 += z2 * z2;
    }
    sc[pi*256 + d]       = s1;
    sc[pi*256 + 64 + d]  = s2 * 0.5f;
    sc[pi*256 + 128 + d] = s3 * (1.f/6.f);
    sc[pi*256 + 192 + d] = s4 * (1.f/24.f);
  }
}

// R15 = R14 with ONE token changed: __launch_bounds__(256,2) -> (256,4).
// R14 post-mortem + full-ledger cross-reference: the launch-bounds min-waves
// arg is the RESIDENCY CAP in this stack -- (256,4)->43% occ (R3), (256,3)->
// 3 slots (R4), (256,2)->2 blocks (R13/R14). R14 had LDS room for 4 blocks
// but declared 2 -> second generation -> 165us. The R2/R3 spill trap at the
// 128-reg budget no longer applies: this fused pipeline compiles at 80 VGPR.
// 4 independent blocks/CU, grid 1024 = single generation, R13-proven
// independent-block overlap at double depth.
// Falsifiers: spill (WRITE>>1MB / VGPR pin 64) -> revert to R13, declare
// 113us floor; no spill + occ ~43% + dur >= 110 -> TLP exhausted, same.
__global__ __launch_bounds__(256, 4)
void Mamba4CTRV18_kernel(
    const float* __restrict__ dense_x, const float* __restrict__ dense_W,
    const float* __restrict__ dense_b, const float* __restrict__ tbl,
    const float* __restrict__ cls, const float* __restrict__ ng,
    const float* __restrict__ nb, const float* __restrict__ xb,
    const float* __restrict__ Dp, const float* __restrict__ ob,
    const float* __restrict__ mb, const float* __restrict__ aib,
    const float* __restrict__ aoW, const float* __restrict__ aob,
    const float* __restrict__ w1, const float* __restrict__ b1,
    const float* __restrict__ w2, const float* __restrict__ b2,
    const float* __restrict__ w3, const float* __restrict__ b3,
    const int* __restrict__ sidx, const unsigned short* __restrict__ wsb,
    float* __restrict__ out) {
  __shared__ __align__(16) unsigned char smem[40960];
  float*          s_seq  = (float*)smem;                     // 40x64 f32 spine (10240)
  unsigned short* s_xnb  = (unsigned short*)(smem + 10240);  // 48x64 bf16 xn / final seq (6144)
  unsigned short* bG0    = (unsigned short*)(smem + 16384);  // gate0->scanout0 ; f32 scratch g0f
  unsigned short* bG1    = (unsigned short*)(smem + 22528);  // gate1->scanout1 ; f32 scratch g1f
  unsigned short* bB0    = (unsigned short*)(smem + 28672);  // Bm0 -> residual bf16 (in-scan) ; tail: K
  unsigned short* bB1    = (unsigned short*)(smem + 34816);  // Bm1 ; tail: V
  float* g0f = (float*)bG0;  // tail: {probs320, q@320..383, seq0@384, c@448} ; phase0: {dx13, idx26}
  float* g1f = (float*)bG1;  // tail: {aopart256, ao@256, mlp1@320, mlp2@448}
  const float* scf = (const float*)(wsb + SC_OFF);
  const float* bpf = (const float*)(wsb + BP_OFF);

  const int tid = threadIdx.x, b = blockIdx.x;
  const int lane = tid & 63, wv = tid >> 6;  // wv 0..3
  const int arow = lane & 15;
  const int aq = (lane >> 4) * 8;
  const int rq = (lane >> 4) * 4;
  const int rq7 = rq & 7;
  const int swA = (arow & 7) << 3;
  const int aqs0 = aq ^ swA, aqs1 = (aq + 32) ^ swA;

  // ---------------- Phase 0: build seq (40 tokens) ----------------
  {
    float* s_dx = g0f;                 // 13 f32
    int* s_idx = (int*)(g0f + 16);     // 26 ints
    if (tid < 13) s_dx[tid] = dense_x[b*13 + tid];
    if (tid >= 64 && tid < 90) {
      int si = tid - 64;
      int v = sidx[b*26 + si];
      v = v < 0 ? 0 : (v > 10000 ? 10000 : v);
      s_idx[si] = v;
    }
    // zero s_xnb pad rows 40..47 (512 u16 = 256 u32) -- stays zero all layers
    ((unsigned int*)(s_xnb + 2560))[tid] = 0u;
    __syncthreads();
    if (tid < 64) s_seq[tid] = cls[tid];
    {
      float x[13];
      #pragma unroll
      for (int k = 0; k < 13; ++k) x[k] = s_dx[k];
      for (int j = tid; j < 832; j += 256) {
        float acc = dense_b[j];
        #pragma unroll
        for (int k = 0; k < 13; ++k) acc = fmaf(x[k], dense_W[j*13 + k], acc);
        s_seq[(1 + (j >> 6))*64 + (j & 63)] = acc;
      }
    }
    for (int e = tid; e < 416; e += 256) {
      int s = e >> 4, c = e & 15;
      const float4* row = (const float4*)(tbl + ((size_t)(s*10001 + s_idx[s]))*64);
      ((float4*)&s_seq[(14 + s)*64])[c] = row[c];
    }
  }
  __syncthreads();

  // ---------------- 4 bidirectional mamba layers ----------------
  for (int L = 0; L < 4; ++L) {
    const int pi0 = 2*L, pi1 = 2*L + 1;

    // LN 4-wide: 40 tokens = 3 sweeps x (4 waves x 4 groups), guard t<40.
    {
      const int g = lane >> 4, dl = lane & 15;
      const int dbase = 4 * ((dl + 4*g) & 15);
      const float4 ngv = *(const float4*)&ng[pi0*64 + dbase];
      const float4 nbv = *(const float4*)&nb[pi0*64 + dbase];
      #pragma unroll 1
      for (int sweep = 0; sweep < 3; ++sweep) {
        int t = sweep*16 + wv*4 + g;  // 0..47, group-uniform guard
        if (t < 40) {
          const float4 xv = *(const float4*)&s_seq[t*64 + dbase];
          float s = (xv.x + xv.y) + (xv.z + xv.w);
          float q = fmaf(xv.x, xv.x, fmaf(xv.y, xv.y, fmaf(xv.z, xv.z, xv.w*xv.w)));
          #pragma unroll
          for (int o = 8; o > 0; o >>= 1) { s += __shfl_xor(s, o, 64); q += __shfl_xor(q, o, 64); }
          float mean = s * (1.f/64.f);
          float var = q * (1.f/64.f) - mean*mean;
          float rs = rsqrtf(var + 1e-5f);
          unsigned short h0 = f2bf(fmaf((xv.x - mean)*rs, ngv.x, nbv.x));
          unsigned short h1 = f2bf(fmaf((xv.y - mean)*rs, ngv.y, nbv.y));
          unsigned short h2 = f2bf(fmaf((xv.z - mean)*rs, ngv.z, nbv.z));
          unsigned short h3 = f2bf(fmaf((xv.w - mean)*rs, ngv.w, nbv.w));
          int o2 = (t << 6) + (dbase ^ ((t & 7) << 3));
          unsigned lo = (unsigned)h0 | ((unsigned)h1 << 16);
          unsigned hi = (unsigned)h2 | ((unsigned)h3 << 16);
          *(uint2*)&s_xnb[o2] = make_uint2(lo, hi);
        }
      }
    }
    __syncthreads();

    // xproj both dirs fused: 2 passes (delta / Bm), wave w -> col-tile
    // (w + cti*4), 3 mt each (48-row tiles; pad outputs garbage, unconsumed).
    {
      #pragma unroll 1
      for (int cti = 0; cti < 2; ++cti) {
        const int j = (wv + cti*4)*16 + arow;  // 0..127
        const unsigned short* Wh0 = wsb + XW_HI + pi0*8192 + j*64;
        const unsigned short* Wl0 = wsb + XW_LO + pi0*8192 + j*64;
        const unsigned short* Wh1 = wsb + XW_HI + pi1*8192 + j*64;
        const unsigned short* Wl1 = wsb + XW_LO + pi1*8192 + j*64;
        bf16x8 bh00 = ld8(Wh0 + aq), bh01 = ld8(Wh0 + 32 + aq);
        bf16x8 bl00 = ld8(Wl0 + aq), bl01 = ld8(Wl0 + 32 + aq);
        bf16x8 bh10 = ld8(Wh1 + aq), bh11 = ld8(Wh1 + 32 + aq);
        bf16x8 bl10 = ld8(Wl1 + aq), bl11 = ld8(Wl1 + 32 + aq);
        const float bj0 = xb[pi0*128 + j], bj1 = xb[pi1*128 + j];
        const bool isDelta = (cti == 0);  // uniform per pass
        float c10=0,c20=0,c30=0,c40=0,c11=0,c21=0,c31=0,c41=0;
        if (isDelta) {
          c10=scf[pi0*256+j]; c20=scf[pi0*256+64+j]; c30=scf[pi0*256+128+j]; c40=scf[pi0*256+192+j];
          c11=scf[pi1*256+j]; c21=scf[pi1*256+64+j]; c31=scf[pi1*256+128+j]; c41=scf[pi1*256+192+j];
        }
        #pragma unroll 1
        for (int mt = 0; mt < 3; ++mt) {
          const unsigned short* A = s_xnb + ((mt*16 + arow) << 6);
          bf16x8 ah0 = ld8(A + aqs0), ah1 = ld8(A + aqs1);
          f32x4 a0 = {0,0,0,0}, a1 = {0,0,0,0};
          a0 = MFMA(ah0, bh00, a0); a0 = MFMA(ah0, bl00, a0);
          a0 = MFMA(ah1, bh01, a0); a0 = MFMA(ah1, bl01, a0);
          a1 = MFMA(ah0, bh10, a1); a1 = MFMA(ah0, bl10, a1);
          a1 = MFMA(ah1, bh11, a1); a1 = MFMA(ah1, bl11, a1);
          const int rbase = mt*16 + rq;
          #pragma unroll
          for (int r = 0; r < 4; ++r) {
            int row = rbase + r;  // 0..47 (pad rows garbage, never consumed)
            int swr = (rq7 + r) << 3;
            float x0v = a0[r] + bj0, x1v = a1[r] + bj1;
            if (isDelta) {
              float sp0 = fmaxf(x0v, 0.f) + __logf(1.f + __expf(-fabsf(x0v)));
              float sp1 = fmaxf(x1v, 0.f) + __logf(1.f + __expf(-fabsf(x1v)));
              int o = (row << 6) + (j ^ swr);
              bG0[o] = f2bf(sp0 * fmaf(sp0, fmaf(sp0, fmaf(sp0, c40, c30), c20), c10));
              bG1[o] = f2bf(sp1 * fmaf(sp1, fmaf(sp1, fmaf(sp1, c41, c31), c21), c11));
            } else {
              int o = (row << 6) + ((j - 64) ^ swr);
              bB0[o] = f2bf(x0v);
              bB1[o] = f2bf(x1v);
            }
          }
        }
      }
    }
    __syncthreads();

    // Scan: wave0 = dir0 (d = lane), wave1 = dir1; 40 scalar steps.
    // dir-0 wave overwrites consumed Bm0 with the bf16 residual (s_seq),
    // building the swizzled residual tile for the fused phase for free.
    if (tid < 128) {
      const int d = lane, dir = wv;  // wave-uniform dir
      unsigned short* bmb = dir ? bB1 : bB0;
      unsigned short* gb = dir ? bG1 : bG0;
      const float dpd = Dp[(pi0 + dir)*64 + d];
      float run = 0.f;
      #pragma unroll
      for (int k = 0; k < 40; ++k) {
        int t = dir ? (39 - k) : k;
        int o = (t << 6) + (d ^ ((t & 7) << 3));
        float xn = bf2f(s_xnb[o]);
        run = fmaf(xn, bf2f(bmb[o]), run);
        float gate = 16.f + bf2f(gb[o]);
        gb[o] = f2bf(fmaf(run, gate, xn * dpd));
        if (dir == 0) bmb[o] = f2bf(s_seq[t*64 + d]);  // wave-uniform branch
      }
    }
    __syncthreads();

    // FUSED out+merge: seq_new = g0@C0^T + g1@C1^T + res@S^T + b'
    // (res tile = bB0). wave w -> col-tile w, 3 mt; writes guarded row<40.
    {
      const int n0 = wv*16 + arow;  // 0..63
      const unsigned short* cbase = wsb + CW + L*24576;
      const unsigned short* C0H = cbase + n0*64;
      const unsigned short* C0L = cbase + 4096 + n0*64;
      const unsigned short* C1H = cbase + 8192 + n0*64;
      const unsigned short* C1L = cbase + 12288 + n0*64;
      const unsigned short* SH  = cbase + 16384 + n0*64;
      const unsigned short* SL  = cbase + 20480 + n0*64;
      bf16x8 c0h0 = ld8(C0H + aq), c0h1 = ld8(C0H + 32 + aq);
      bf16x8 c0l0 = ld8(C0L + aq), c0l1 = ld8(C0L + 32 + aq);
      bf16x8 c1h0 = ld8(C1H + aq), c1h1 = ld8(C1H + 32 + aq);
      bf16x8 c1l0 = ld8(C1L + aq), c1l1 = ld8(C1L + 32 + aq);
      bf16x8 sh0 = ld8(SH + aq), sh1 = ld8(SH + 32 + aq);
      bf16x8 sl0 = ld8(SL + aq), sl1 = ld8(SL + 32 + aq);
      const float bom = bpf[L*64 + n0];
      #pragma unroll 1
      for (int mt = 0; mt < 3; ++mt) {
        const unsigned short* A0 = bG0 + ((mt*16 + arow) << 6);
        const unsigned short* A1 = bG1 + ((mt*16 + arow) << 6);
        const unsigned short* AR = bB0 + ((mt*16 + arow) << 6);
        bf16x8 g00 = ld8(A0 + aqs0), g01 = ld8(A0 + aqs1);
        bf16x8 g10 = ld8(A1 + aqs0), g11 = ld8(A1 + aqs1);
        bf16x8 r0 = ld8(AR + aqs0), r1 = ld8(AR + aqs1);
        f32x4 a0 = {0,0,0,0}, a1 = {0,0,0,0}, a2 = {0,0,0,0};
        a0 = MFMA(g00, c0h0, a0); a0 = MFMA(g00, c0l0, a0);
        a0 = MFMA(g01, c0h1, a0); a0 = MFMA(g01, c0l1, a0);
        a1 = MFMA(g10, c1h0, a1); a1 = MFMA(g10, c1l0, a1);
        a1 = MFMA(g11, c1h1, a1); a1 = MFMA(g11, c1l1, a1);
        a2 = MFMA(r0, sh0, a2); a2 = MFMA(r0, sl0, a2);
        a2 = MFMA(r1, sh1, a2); a2 = MFMA(r1, sl1, a2);
        const int rbase = mt*16 + rq;
        #pragma unroll
        for (int r = 0; r < 4; ++r) {
          int row = rbase + r;
          if (row < 40) {
            float v = a0[r] + a1[r] + a2[r] + bom;
            s_seq[row*64 + n0] = v;
            if (L == 3) s_xnb[(row << 6) + (n0 ^ ((rq7 + r) << 3))] = f2bf(v);
          }
        }
      }
    }
    __syncthreads();
  }

  // ---------------- Attention tail ----------------
  // QKV: 28 units (K/V: 8 ct x 3 mt = 24; Q: 4 ct x mt0 = 4) over 4 waves = 7 each
  {
    #pragma unroll 1
    for (int i = 0; i < 7; ++i) {
      const int u = wv + 4*i;  // 0..27
      int j, mtk;
      if (u < 24) { j = 64 + (u & 7)*16 + arow; mtk = u >> 3; }
      else { int qi = u - 24; j = qi*16 + arow; mtk = 0; }
      const unsigned short* Wh = wsb + AI_HI + j*64;
      const unsigned short* Wl = wsb + AI_LO + j*64;
      bf16x8 bh0 = ld8(Wh + aq), bh1 = ld8(Wh + 32 + aq);
      bf16x8 bl0 = ld8(Wl + aq), bl1 = ld8(Wl + 32 + aq);
      const float bj = aib[j];
      const unsigned short* A = s_xnb + ((mtk*16 + arow) << 6);
      bf16x8 ah0 = ld8(A + aqs0), ah1 = ld8(A + aqs1);
      f32x4 a0 = {0,0,0,0};
      a0 = MFMA(ah0, bh0, a0); a0 = MFMA(ah0, bl0, a0);
      a0 = MFMA(ah1, bh1, a0); a0 = MFMA(ah1, bl1, a0);
      const int rbase = mtk*16 + rq;
      #pragma unroll
      for (int r = 0; r < 4; ++r) {
        int row = rbase + r;
        int swr = (rq7 + r) << 3;
        float val = a0[r] + bj;
        if (u < 24) {  // K/V; pad rows 40..47 written but never read
          if (j < 128) bB0[(row << 6) + ((j - 64) ^ swr)] = f2bf(val);   // K
          else         bB1[(row << 6) + ((j - 128) ^ swr)] = f2bf(val);  // V
        } else {
          if (row == 0) g0f[320 + j] = val;  // q vector
        }
      }
    }
    if (tid < 64) g0f[384 + tid] = s_seq[tid];  // seq token 0
  }
  __syncthreads();

  // logits: 8 heads x 40 keys = 320
  for (int e = tid; e < 320; e += 256) {
    int h = e / 40, kk = e - h*40;
    int kbase = (kk << 6) + ((h*8) ^ ((kk & 7) << 3));  // h*8 mult of 8: +i stays in chunk
    float acc = 0.f;
    #pragma unroll
    for (int i = 0; i < 8; ++i)
      acc += g0f[320 + h*8 + i] * bf2f(bB0[kbase + i]);
    g0f[e] = acc * 0.35355339059327373f;
  }
  __syncthreads();

  // softmax: 8 heads over 4 waves, 32 lanes per head (40 keys = 32+8)
  {
    const int hh = wv*2 + (lane >> 5), jl = lane & 31;
    float* pr = g0f + hh*40;
    float a = pr[jl];
    float bv = (jl < 8) ? pr[32 + jl] : -1e30f;
    float m = fmaxf(a, bv);
    #pragma unroll
    for (int o = 16; o > 0; o >>= 1) m = fmaxf(m, __shfl_xor(m, o, 32));
    float pa = __expf(a - m), pb = (jl < 8) ? __expf(bv - m) : 0.f;
    float s = pa + pb;
    #pragma unroll
    for (int o = 16; o > 0; o >>= 1) s += __shfl_xor(s, o, 32);
    float inv = 1.f / s;
    pr[jl] = pa * inv;
    if (jl < 8) pr[32 + jl] = pb * inv;
  }
  __syncthreads();

  // ao partials: 4 quarters x 64 d = 256 exactly
  {
    const int d = tid & 63, qrt = tid >> 6, hh = d >> 3;
    float acc = 0.f;
    #pragma unroll
    for (int k = qrt*10; k < qrt*10 + 10; ++k) {
      int o = (k << 6) + (d ^ ((k & 7) << 3));
      acc += g0f[hh*40 + k] * bf2f(bB1[o]);
    }
    g1f[qrt*64 + d] = acc;
  }
  __syncthreads();
  if (tid < 64) {
    g1f[256 + tid] = g1f[tid] + g1f[64 + tid] + g1f[128 + tid] + g1f[192 + tid];
  }
  __syncthreads();

  // c = seq0 + ao @ aoW.T + aob
  if (tid < 64) {
    g0f[448 + tid] = g0f[384 + tid] + aob[tid]
                   + dotg64(&g1f[256], aoW + (size_t)tid*64);
  }
  __syncthreads();

  // MLP1
  if (tid < 128) {
    g1f[320 + tid] = fmaxf(b1[tid] + dotg64(&g0f[448], w1 + (size_t)tid*64), 0.f);
  }
  __syncthreads();

  // MLP2
  if (tid < 64) {
    float acc = dotg64(&g1f[320], w2 + (size_t)tid*128)
              + dotg64(&g1f[384], w2 + (size_t)tid*128 + 64);
    g1f[448 + tid] = fmaxf(acc + b2[tid], 0.f);
  }
  __syncthreads();

  if (tid < 64) {
    float v = g1f[448 + lane] * w3[lane];
    v = wred64(v);
    if (lane == 0) out[b] = v + b3[0];
  }
}

extern "C" void kernel_launch(void* const* d_in, const int* in_sizes, int n_in,
                              void* d_out, int out_size, void* d_ws, size_t ws_size,
                              hipStream_t stream) {
  (void)n_in; (void)ws_size; (void)out_size;
  const float* dense_x = (const float*)d_in[0];
  const float* dense_W = (const float*)d_in[1];
  const float* dense_b = (const float*)d_in[2];
  const float* tbl     = (const float*)d_in[3];
  const float* cls     = (const float*)d_in[4];
  const float* ng      = (const float*)d_in[5];
  const float* nb      = (const float*)d_in[6];
  const float* xW      = (const float*)d_in[7];
  const float* xb      = (const float*)d_in[8];
  const float* Ap      = (const float*)d_in[9];
  const float* Dp      = (const float*)d_in[10];
  const float* oW      = (const float*)d_in[11];
  const float* ob      = (const float*)d_in[12];
  const float* mW      = (const float*)d_in[13];
  const float* mb      = (const float*)d_in[14];
  const float* aiW     = (const float*)d_in[15];
  const float* aib     = (const float*)d_in[16];
  const float* aoW     = (const float*)d_in[17];
  const float* aob     = (const float*)d_in[18];
  const float* w1      = (const float*)d_in[19];
  const float* b1      = (const float*)d_in[20];
  const float* w2      = (const float*)d_in[21];
  const float* b2      = (const float*)d_in[22];
  const float* w3      = (const float*)d_in[23];
  const float* b3      = (const float*)d_in[24];
  const int*   sidx    = (const int*)d_in[25];
  float* out = (float*)d_out;
  unsigned short* wsb = (unsigned short*)d_ws;

  hipLaunchKernelGGL(prep_kernel, dim3(256), dim3(256), 0, stream,
                     xW, oW, ob, mW, mb, aiW, Ap, wsb);

  const int B = in_sizes[0] / 13;  // 1024
  hipLaunchKernelGGL(Mamba4CTRV18_kernel, dim3(B), dim3(256), 0, stream,
                     dense_x, dense_W, dense_b, tbl, cls, ng, nb, xb, Dp, ob, mb,
                     aib, aoW, aob, w1, b1, w2, b2, w3, b3, sidx, wsb, out);
}

// Round 16
// 241.562 us; speedup vs baseline: 1.2471x; 1.0357x over previous
//
#include <hip/hip_runtime.h>

#define DEV static __device__ __forceinline__

typedef __attribute__((ext_vector_type(8))) short bf16x8;
typedef __attribute__((ext_vector_type(4))) float f32x4;

#define MFMA(a, b, c) __builtin_amdgcn_mfma_f32_16x16x32_bf16(a, b, c, 0, 0, 0)

DEV float bf2f(unsigned short h) { return __uint_as_float(((unsigned)h) << 16); }
DEV unsigned short f2bf(float f) {
  unsigned u = __float_as_uint(f);
  u += 0x7fffu + ((u >> 16) & 1u);
  return (unsigned short)(u >> 16);
}
DEV bf16x8 ld8(const unsigned short* p) { return *(const bf16x8*)p; }

DEV float dotg64(const float* x, const float* wrow) {
  const float4* wp = (const float4*)wrow;
  float a0 = 0.f, a1 = 0.f;
  #pragma unroll
  for (int c = 0; c < 8; ++c) {
    float4 u = wp[2*c], v = wp[2*c + 1];
    a0 = fmaf(u.x, x[8*c+0], a0); a0 = fmaf(u.y, x[8*c+1], a0);
    a0 = fmaf(u.z, x[8*c+2], a0); a0 = fmaf(u.w, x[8*c+3], a0);
    a1 = fmaf(v.x, x[8*c+4], a1); a1 = fmaf(v.y, x[8*c+5], a1);
    a1 = fmaf(v.z, x[8*c+6], a1); a1 = fmaf(v.w, x[8*c+7], a1);
  }
  return a0 + a1;
}
DEV float wred64(float v) {
  #pragma unroll
  for (int o = 32; o > 0; o >>= 1) v += __shfl_xor(v, o, 64);
  return v;
}

// d_ws layout (ushort element offsets): weights as bf16 hi/lo pairs.
// Fused composites: C0 = mW0@oW0, C1 = mW1@oW1, S = mW0+mW1 (hi/lo each),
// b' = mb + mW0@ob0 + mW1@ob1.
#define XW_HI 0        // 4*2*128*64 = 65536
#define XW_LO 65536
#define CW 131072      // per layer 24576: C0H,C0L,C1H,C1L,SH,SL (each 4096)
#define AI_HI 262144
#define AI_LO 274432
#define SC_OFF 286720  // f32: 8*256 gate-poly coefs
#define BP_OFF 290816  // f32: 4*64 fused bias b'

// bf16 tiles: 48 rows x 64 cols (40 real + 8 pad), stride 64, XOR swizzle
// elem(row,d) = (row<<6) + (d ^ ((row&7)<<3)).

__global__ void prep_kernel(const float* __restrict__ xW, const float* __restrict__ oW,
                            const float* __restrict__ ob, const float* __restrict__ mW,
                            const float* __restrict__ mb, const float* __restrict__ aiW,
                            const float* __restrict__ Ap, unsigned short* __restrict__ wsb) {
  const int gid = blockIdx.x * blockDim.x + threadIdx.x;
  const int stride = gridDim.x * blockDim.x;
  for (int i = gid; i < 65536; i += stride) {
    float x = xW[i]; unsigned short h = f2bf(x);
    wsb[XW_HI + i] = h; wsb[XW_LO + i] = f2bf(x - bf2f(h));
  }
  for (int i = gid; i < 32768; i += stride) {
    int L = i >> 13, rem = i & 8191;
    int dir = rem >> 12, n = (rem >> 6) & 63, d = rem & 63;
    const float* mrow = mW + L*8192 + n*128 + dir*64;
    const float* ocol = oW + L*8192 + dir*4096 + d;
    float acc = 0.f;
    #pragma unroll 8
    for (int j = 0; j < 64; ++j) acc = fmaf(mrow[j], ocol[j*64], acc);
    unsigned short h = f2bf(acc);
    int base = CW + L*24576 + dir*8192;
    wsb[base + n*64 + d] = h;
    wsb[base + 4096 + n*64 + d] = f2bf(acc - bf2f(h));
  }
  for (int i = gid; i < 16384; i += stride) {
    int L = i >> 12, n = (i >> 6) & 63, j = i & 63;
    float v = mW[L*8192 + n*128 + j] + mW[L*8192 + n*128 + 64 + j];
    unsigned short h = f2bf(v);
    int base = CW + L*24576 + 16384;
    wsb[base + n*64 + j] = h;
    wsb[base + 4096 + n*64 + j] = f2bf(v - bf2f(h));
  }
  {
    float* bp = (float*)(wsb + BP_OFF);
    for (int i = gid; i < 256; i += stride) {
      int L = i >> 6, n = i & 63;
      const float* mrow = mW + L*8192 + n*128;
      float acc = mb[L*64 + n];
      #pragma unroll 8
      for (int j = 0; j < 64; ++j) acc = fmaf(ob[(2*L)*64 + j], mrow[j], acc);
      #pragma unroll 8
      for (int j = 0; j < 64; ++j) acc = fmaf(ob[(2*L+1)*64 + j], mrow[64 + j], acc);
      bp[i] = acc;
    }
  }
  for (int i = gid; i < 12288; i += stride) {
    float x = aiW[i]; unsigned short h = f2bf(x);
    wsb[AI_HI + i] = h; wsb[AI_LO + i] = f2bf(x - bf2f(h));
  }
  float* sc = (float*)(wsb + SC_OFF);
  for (int i = gid; i < 512; i += stride) {
    int pi = i >> 6, d = i & 63;
    const float* a = Ap + (size_t)i * 16;
    float s1 = 0, s2 = 0, s3 = 0, s4 = 0;
    #pragma unroll
    for (int n = 0; n < 16; ++n) {
      float z = a[n]; float z2 = z * z;
      s1 += z; s2 += z2; s3 += z2 * z; s4 += z2 * z2;
    }
    sc[pi*256 + d]       = s1;
    sc[pi*256 + 64 + d]  = s2 * 0.5f;
    sc[pi*256 + 128 + d] = s3 * (1.f/6.f);
    sc[pi*256 + 192 + d] = s4 * (1.f/24.f);
  }
}

// R16 = R15 + one-phase-ahead weight prefetch (the safe form of R7's idea).
// R15 post-mortem: 4 blocks/CU at 40% occ, zero spill, dur 113.7 ~= R13's
// 113.2 -> throughput invariant 4 rows/CU/113us across 2x2row and 4x1row
// configs = shared per-CU ceiling, but NO measured pipe saturated (VALU 42%,
// MFMA 8.6%). Un-probed path component: post-barrier L2 weight-load latency
// (8-12 frags x ~200-500cyc, 3x/layer, serialized on the critical path).
// R7's spill came from 16-24 frags over MULTIPLE barriers at a pinned-128
// budget; here: base 64 VGPR at 128 budget, ONE phase distance: (a) delta
// xproj weights (8 frags,+32reg) issued before LN; (b) fused composites
// (12 frags,+48reg) issued before scan (waves 2-3 idle there). Peak ~112<=128.
// Falsifiers: spill/occ-drop -> revert R15; flat no-spill -> declare the
// 4rows/113us invariant the structural floor (<<ROOFLINE>> next round).
__global__ __launch_bounds__(256, 4)
void Mamba4CTRV19_kernel(
    const float* __restrict__ dense_x, const float* __restrict__ dense_W,
    const float* __restrict__ dense_b, const float* __restrict__ tbl,
    const float* __restrict__ cls, const float* __restrict__ ng,
    const float* __restrict__ nb, const float* __restrict__ xb,
    const float* __restrict__ Dp, const float* __restrict__ ob,
    const float* __restrict__ mb, const float* __restrict__ aib,
    const float* __restrict__ aoW, const float* __restrict__ aob,
    const float* __restrict__ w1, const float* __restrict__ b1,
    const float* __restrict__ w2, const float* __restrict__ b2,
    const float* __restrict__ w3, const float* __restrict__ b3,
    const int* __restrict__ sidx, const unsigned short* __restrict__ wsb,
    float* __restrict__ out) {
  __shared__ __align__(16) unsigned char smem[40960];
  float*          s_seq  = (float*)smem;                     // 40x64 f32 spine (10240)
  unsigned short* s_xnb  = (unsigned short*)(smem + 10240);  // 48x64 bf16 xn / final seq (6144)
  unsigned short* bG0    = (unsigned short*)(smem + 16384);  // gate0->scanout0 ; f32 scratch g0f
  unsigned short* bG1    = (unsigned short*)(smem + 22528);  // gate1->scanout1 ; f32 scratch g1f
  unsigned short* bB0    = (unsigned short*)(smem + 28672);  // Bm0 -> residual bf16 (in-scan) ; tail: K
  unsigned short* bB1    = (unsigned short*)(smem + 34816);  // Bm1 ; tail: V
  float* g0f = (float*)bG0;  // tail: {probs320, q@320..383, seq0@384, c@448} ; phase0: {dx13, idx26}
  float* g1f = (float*)bG1;  // tail: {aopart256, ao@256, mlp1@320, mlp2@448}
  const float* scf = (const float*)(wsb + SC_OFF);
  const float* bpf = (const float*)(wsb + BP_OFF);

  const int tid = threadIdx.x, b = blockIdx.x;
  const int lane = tid & 63, wv = tid >> 6;  // wv 0..3
  const int arow = lane & 15;
  const int aq = (lane >> 4) * 8;
  const int rq = (lane >> 4) * 4;
  const int rq7 = rq & 7;
  const int swA = (arow & 7) << 3;
  const int aqs0 = aq ^ swA, aqs1 = (aq + 32) ^ swA;

  // ---------------- Phase 0: build seq (40 tokens) ----------------
  {
    float* s_dx = g0f;                 // 13 f32
    int* s_idx = (int*)(g0f + 16);     // 26 ints
    if (tid < 13) s_dx[tid] = dense_x[b*13 + tid];
    if (tid >= 64 && tid < 90) {
      int si = tid - 64;
      int v = sidx[b*26 + si];
      v = v < 0 ? 0 : (v > 10000 ? 10000 : v);
      s_idx[si] = v;
    }
    // zero s_xnb pad rows 40..47 (512 u16 = 256 u32) -- stays zero all layers
    ((unsigned int*)(s_xnb + 2560))[tid] = 0u;
    __syncthreads();
    if (tid < 64) s_seq[tid] = cls[tid];
    {
      float x[13];
      #pragma unroll
      for (int k = 0; k < 13; ++k) x[k] = s_dx[k];
      for (int j = tid; j < 832; j += 256) {
        float acc = dense_b[j];
        #pragma unroll
        for (int k = 0; k < 13; ++k) acc = fmaf(x[k], dense_W[j*13 + k], acc);
        s_seq[(1 + (j >> 6))*64 + (j & 63)] = acc;
      }
    }
    for (int e = tid; e < 416; e += 256) {
      int s = e >> 4, c = e & 15;
      const float4* row = (const float4*)(tbl + ((size_t)(s*10001 + s_idx[s]))*64);
      ((float4*)&s_seq[(14 + s)*64])[c] = row[c];
    }
  }
  __syncthreads();

  // ---------------- 4 bidirectional mamba layers ----------------
  for (int L = 0; L < 4; ++L) {
    const int pi0 = 2*L, pi1 = 2*L + 1;

    // ---- prefetch delta-pass xproj weights (consumed after the LN barrier).
    // Issued here so ~L2 latency hides under LN. 8 frags = +32 regs.
    const int jd = wv*16 + arow;  // delta col 0..63
    bf16x8 pd00, pd01, pd02, pd03, pd10, pd11, pd12, pd13;
    {
      const unsigned short* Wh0 = wsb + XW_HI + pi0*8192 + jd*64;
      const unsigned short* Wl0 = wsb + XW_LO + pi0*8192 + jd*64;
      const unsigned short* Wh1 = wsb + XW_HI + pi1*8192 + jd*64;
      const unsigned short* Wl1 = wsb + XW_LO + pi1*8192 + jd*64;
      pd00 = ld8(Wh0 + aq); pd01 = ld8(Wh0 + 32 + aq);
      pd02 = ld8(Wl0 + aq); pd03 = ld8(Wl0 + 32 + aq);
      pd10 = ld8(Wh1 + aq); pd11 = ld8(Wh1 + 32 + aq);
      pd12 = ld8(Wl1 + aq); pd13 = ld8(Wl1 + 32 + aq);
    }

    // LN 4-wide: 40 tokens = 3 sweeps x (4 waves x 4 groups), guard t<40.
    {
      const int g = lane >> 4, dl = lane & 15;
      const int dbase = 4 * ((dl + 4*g) & 15);
      const float4 ngv = *(const float4*)&ng[pi0*64 + dbase];
      const float4 nbv = *(const float4*)&nb[pi0*64 + dbase];
      #pragma unroll 1
      for (int sweep = 0; sweep < 3; ++sweep) {
        int t = sweep*16 + wv*4 + g;  // 0..47, group-uniform guard
        if (t < 40) {
          const float4 xv = *(const float4*)&s_seq[t*64 + dbase];
          float s = (xv.x + xv.y) + (xv.z + xv.w);
          float q = fmaf(xv.x, xv.x, fmaf(xv.y, xv.y, fmaf(xv.z, xv.z, xv.w*xv.w)));
          #pragma unroll
          for (int o = 8; o > 0; o >>= 1) { s += __shfl_xor(s, o, 64); q += __shfl_xor(q, o, 64); }
          float mean = s * (1.f/64.f);
          float var = q * (1.f/64.f) - mean*mean;
          float rs = rsqrtf(var + 1e-5f);
          unsigned short h0 = f2bf(fmaf((xv.x - mean)*rs, ngv.x, nbv.x));
          unsigned short h1 = f2bf(fmaf((xv.y - mean)*rs, ngv.y, nbv.y));
          unsigned short h2 = f2bf(fmaf((xv.z - mean)*rs, ngv.z, nbv.z));
          unsigned short h3 = f2bf(fmaf((xv.w - mean)*rs, ngv.w, nbv.w));
          int o2 = (t << 6) + (dbase ^ ((t & 7) << 3));
          unsigned lo = (unsigned)h0 | ((unsigned)h1 << 16);
          unsigned hi = (unsigned)h2 | ((unsigned)h3 << 16);
          *(uint2*)&s_xnb[o2] = make_uint2(lo, hi);
        }
      }
    }
    __syncthreads();

    // xproj pass 0 (delta): prefetched weights; pass 1 (Bm): inline loads
    // (their latency partially hides under pass 0's compute).
    {
      // pass 0: delta cols jd, dst bG*
      {
        const float bj0 = xb[pi0*128 + jd], bj1 = xb[pi1*128 + jd];
        const float c10=scf[pi0*256+jd], c20=scf[pi0*256+64+jd],
                    c30=scf[pi0*256+128+jd], c40=scf[pi0*256+192+jd];
        const float c11=scf[pi1*256+jd], c21=scf[pi1*256+64+jd],
                    c31=scf[pi1*256+128+jd], c41=scf[pi1*256+192+jd];
        #pragma unroll 1
        for (int mt = 0; mt < 3; ++mt) {
          const unsigned short* A = s_xnb + ((mt*16 + arow) << 6);
          bf16x8 ah0 = ld8(A + aqs0), ah1 = ld8(A + aqs1);
          f32x4 a0 = {0,0,0,0}, a1 = {0,0,0,0};
          a0 = MFMA(ah0, pd00, a0); a0 = MFMA(ah0, pd02, a0);
          a0 = MFMA(ah1, pd01, a0); a0 = MFMA(ah1, pd03, a0);
          a1 = MFMA(ah0, pd10, a1); a1 = MFMA(ah0, pd12, a1);
          a1 = MFMA(ah1, pd11, a1); a1 = MFMA(ah1, pd13, a1);
          const int rbase = mt*16 + rq;
          #pragma unroll
          for (int r = 0; r < 4; ++r) {
            int row = rbase + r;
            int swr = (rq7 + r) << 3;
            float x0v = a0[r] + bj0, x1v = a1[r] + bj1;
            float sp0 = fmaxf(x0v, 0.f) + __logf(1.f + __expf(-fabsf(x0v)));
            float sp1 = fmaxf(x1v, 0.f) + __logf(1.f + __expf(-fabsf(x1v)));
            int o = (row << 6) + (jd ^ swr);
            bG0[o] = f2bf(sp0 * fmaf(sp0, fmaf(sp0, fmaf(sp0, c40, c30), c20), c10));
            bG1[o] = f2bf(sp1 * fmaf(sp1, fmaf(sp1, fmaf(sp1, c41, c31), c21), c11));
          }
        }
      }
      // pass 1: Bm cols j = 64 + jd, dst bB*
      {
        const int j = 64 + jd;
        const unsigned short* Wh0 = wsb + XW_HI + pi0*8192 + j*64;
        const unsigned short* Wl0 = wsb + XW_LO + pi0*8192 + j*64;
        const unsigned short* Wh1 = wsb + XW_HI + pi1*8192 + j*64;
        const unsigned short* Wl1 = wsb + XW_LO + pi1*8192 + j*64;
        bf16x8 bh00 = ld8(Wh0 + aq), bh01 = ld8(Wh0 + 32 + aq);
        bf16x8 bl00 = ld8(Wl0 + aq), bl01 = ld8(Wl0 + 32 + aq);
        bf16x8 bh10 = ld8(Wh1 + aq), bh11 = ld8(Wh1 + 32 + aq);
        bf16x8 bl10 = ld8(Wl1 + aq), bl11 = ld8(Wl1 + 32 + aq);
        const float bj0 = xb[pi0*128 + j], bj1 = xb[pi1*128 + j];
        #pragma unroll 1
        for (int mt = 0; mt < 3; ++mt) {
          const unsigned short* A = s_xnb + ((mt*16 + arow) << 6);
          bf16x8 ah0 = ld8(A + aqs0), ah1 = ld8(A + aqs1);
          f32x4 a0 = {0,0,0,0}, a1 = {0,0,0,0};
          a0 = MFMA(ah0, bh00, a0); a0 = MFMA(ah0, bl00, a0);
          a0 = MFMA(ah1, bh01, a0); a0 = MFMA(ah1, bl01, a0);
          a1 = MFMA(ah0, bh10, a1); a1 = MFMA(ah0, bl10, a1);
          a1 = MFMA(ah1, bh11, a1); a1 = MFMA(ah1, bl11, a1);
          const int rbase = mt*16 + rq;
          #pragma unroll
          for (int r = 0; r < 4; ++r) {
            int row = rbase + r;
            int swr = (rq7 + r) << 3;
            int o = (row << 6) + (jd ^ swr);  // (j-64) == jd
            bB0[o] = f2bf(a0[r] + bj0);
            bB1[o] = f2bf(a1[r] + bj1);
          }
        }
      }
    }
    __syncthreads();

    // ---- prefetch fused-phase composites (consumed after the scan barrier).
    // Issued by ALL waves; waves 2-3 are idle through the scan, so the ~L2
    // latency flies under it. 12 frags = +48 regs.
    const int n0 = wv*16 + arow;  // 0..63
    bf16x8 c0h0, c0h1, c0l0, c0l1, c1h0, c1h1, c1l0, c1l1, sh0, sh1, sl0, sl1;
    {
      const unsigned short* cbase = wsb + CW + L*24576;
      const unsigned short* C0H = cbase + n0*64;
      const unsigned short* C0L = cbase + 4096 + n0*64;
      const unsigned short* C1H = cbase + 8192 + n0*64;
      const unsigned short* C1L = cbase + 12288 + n0*64;
      const unsigned short* SH  = cbase + 16384 + n0*64;
      const unsigned short* SL  = cbase + 20480 + n0*64;
      c0h0 = ld8(C0H + aq); c0h1 = ld8(C0H + 32 + aq);
      c0l0 = ld8(C0L + aq); c0l1 = ld8(C0L + 32 + aq);
      c1h0 = ld8(C1H + aq); c1h1 = ld8(C1H + 32 + aq);
      c1l0 = ld8(C1L + aq); c1l1 = ld8(C1L + 32 + aq);
      sh0 = ld8(SH + aq); sh1 = ld8(SH + 32 + aq);
      sl0 = ld8(SL + aq); sl1 = ld8(SL + 32 + aq);
    }
    const float bom = bpf[L*64 + n0];

    // Scan: wave0 = dir0 (d = lane), wave1 = dir1; 40 scalar steps.
    // dir-0 wave overwrites consumed Bm0 with the bf16 residual (s_seq).
    if (tid < 128) {
      const int d = lane, dir = wv;  // wave-uniform dir
      unsigned short* bmb = dir ? bB1 : bB0;
      unsigned short* gb = dir ? bG1 : bG0;
      const float dpd = Dp[(pi0 + dir)*64 + d];
      float run = 0.f;
      #pragma unroll
      for (int k = 0; k < 40; ++k) {
        int t = dir ? (39 - k) : k;
        int o = (t << 6) + (d ^ ((t & 7) << 3));
        float xn = bf2f(s_xnb[o]);
        run = fmaf(xn, bf2f(bmb[o]), run);
        float gate = 16.f + bf2f(gb[o]);
        gb[o] = f2bf(fmaf(run, gate, xn * dpd));
        if (dir == 0) bmb[o] = f2bf(s_seq[t*64 + d]);  // wave-uniform branch
      }
    }
    __syncthreads();

    // FUSED out+merge (prefetched weights): seq_new = g0@C0^T + g1@C1^T +
    // res@S^T + b' (res tile = bB0). 3 mt; writes guarded row<40.
    {
      #pragma unroll 1
      for (int mt = 0; mt < 3; ++mt) {
        const unsigned short* A0 = bG0 + ((mt*16 + arow) << 6);
        const unsigned short* A1 = bG1 + ((mt*16 + arow) << 6);
        const unsigned short* AR = bB0 + ((mt*16 + arow) << 6);
        bf16x8 g00 = ld8(A0 + aqs0), g01 = ld8(A0 + aqs1);
        bf16x8 g10 = ld8(A1 + aqs0), g11 = ld8(A1 + aqs1);
        bf16x8 r0 = ld8(AR + aqs0), r1 = ld8(AR + aqs1);
        f32x4 a0 = {0,0,0,0}, a1 = {0,0,0,0}, a2 = {0,0,0,0};
        a0 = MFMA(g00, c0h0, a0); a0 = MFMA(g00, c0l0, a0);
        a0 = MFMA(g01, c0h1, a0); a0 = MFMA(g01, c0l1, a0);
        a1 = MFMA(g10, c1h0, a1); a1 = MFMA(g10, c1l0, a1);
        a1 = MFMA(g11, c1h1, a1); a1 = MFMA(g11, c1l1, a1);
        a2 = MFMA(r0, sh0, a2); a2 = MFMA(r0, sl0, a2);
        a2 = MFMA(r1, sh1, a2); a2 = MFMA(r1, sl1, a2);
        const int rbase = mt*16 + rq;
        #pragma unroll
        for (int r = 0; r < 4; ++r) {
          int row = rbase + r;
          if (row < 40) {
            float v = a0[r] + a1[r] + a2[r] + bom;
            s_seq[row*64 + n0] = v;
            if (L == 3) s_xnb[(row << 6) + (n0 ^ ((rq7 + r) << 3))] = f2bf(v);
          }
        }
      }
    }
    __syncthreads();
  }

  // ---------------- Attention tail ----------------
  // QKV: 28 units (K/V: 8 ct x 3 mt = 24; Q: 4 ct x mt0 = 4) over 4 waves = 7 each
  {
    #pragma unroll 1
    for (int i = 0; i < 7; ++i) {
      const int u = wv + 4*i;  // 0..27
      int j, mtk;
      if (u < 24) { j = 64 + (u & 7)*16 + arow; mtk = u >> 3; }
      else { int qi = u - 24; j = qi*16 + arow; mtk = 0; }
      const unsigned short* Wh = wsb + AI_HI + j*64;
      const unsigned short* Wl = wsb + AI_LO + j*64;
      bf16x8 bh0 = ld8(Wh + aq), bh1 = ld8(Wh + 32 + aq);
      bf16x8 bl0 = ld8(Wl + aq), bl1 = ld8(Wl + 32 + aq);
      const float bj = aib[j];
      const unsigned short* A = s_xnb + ((mtk*16 + arow) << 6);
      bf16x8 ah0 = ld8(A + aqs0), ah1 = ld8(A + aqs1);
      f32x4 a0 = {0,0,0,0};
      a0 = MFMA(ah0, bh0, a0); a0 = MFMA(ah0, bl0, a0);
      a0 = MFMA(ah1, bh1, a0); a0 = MFMA(ah1, bl1, a0);
      const int rbase = mtk*16 + rq;
      #pragma unroll
      for (int r = 0; r < 4; ++r) {
        int row = rbase + r;
        int swr = (rq7 + r) << 3;
        float val = a0[r] + bj;
        if (u < 24) {  // K/V; pad rows 40..47 written but never read
          if (j < 128) bB0[(row << 6) + ((j - 64) ^ swr)] = f2bf(val);   // K
          else         bB1[(row << 6) + ((j - 128) ^ swr)] = f2bf(val);  // V
        } else {
          if (row == 0) g0f[320 + j] = val;  // q vector
        }
      }
    }
    if (tid < 64) g0f[384 + tid] = s_seq[tid];  // seq token 0
  }
  __syncthreads();

  // logits: 8 heads x 40 keys = 320
  for (int e = tid; e < 320; e += 256) {
    int h = e / 40, kk = e - h*40;
    int kbase = (kk << 6) + ((h*8) ^ ((kk & 7) << 3));  // h*8 mult of 8: +i stays in chunk
    float acc = 0.f;
    #pragma unroll
    for (int i = 0; i < 8; ++i)
      acc += g0f[320 + h*8 + i] * bf2f(bB0[kbase + i]);
    g0f[e] = acc * 0.35355339059327373f;
  }
  __syncthreads();

  // softmax: 8 heads over 4 waves, 32 lanes per head (40 keys = 32+8)
  {
    const int hh = wv*2 + (lane >> 5), jl = lane & 31;
    float* pr = g0f + hh*40;
    float a = pr[jl];
    float bv = (jl < 8) ? pr[32 + jl] : -1e30f;
    float m = fmaxf(a, bv);
    #pragma unroll
    for (int o = 16; o > 0; o >>= 1) m = fmaxf(m, __shfl_xor(m, o, 32));
    float pa = __expf(a - m), pb = (jl < 8) ? __expf(bv - m) : 0.f;
    float s = pa + pb;
    #pragma unroll
    for (int o = 16; o > 0; o >>= 1) s += __shfl_xor(s, o, 32);
    float inv = 1.f / s;
    pr[jl] = pa * inv;
    if (jl < 8) pr[32 + jl] = pb * inv;
  }
  __syncthreads();

  // ao partials: 4 quarters x 64 d = 256 exactly
  {
    const int d = tid & 63, qrt = tid >> 6, hh = d >> 3;
    float acc = 0.f;
    #pragma unroll
    for (int k = qrt*10; k < qrt*10 + 10; ++k) {
      int o = (k << 6) + (d ^ ((k & 7) << 3));
      acc += g0f[hh*40 + k] * bf2f(bB1[o]);
    }
    g1f[qrt*64 + d] = acc;
  }
  __syncthreads();
  if (tid < 64) {
    g1f[256 + tid] = g1f[tid] + g1f[64 + tid] + g1f[128 + tid] + g1f[192 + tid];
  }
  __syncthreads();

  // c = seq0 + ao @ aoW.T + aob
  if (tid < 64) {
    g0f[448 + tid] = g0f[384 + tid] + aob[tid]
                   + dotg64(&g1f[256], aoW + (size_t)tid*64);
  }
  __syncthreads();

  // MLP1
  if (tid < 128) {
    g1f[320 + tid] = fmaxf(b1[tid] + dotg64(&g0f[448], w1 + (size_t)tid*64), 0.f);
  }
  __syncthreads();

  // MLP2
  if (tid < 64) {
    float acc = dotg64(&g1f[320], w2 + (size_t)tid*128)
              + dotg64(&g1f[384], w2 + (size_t)tid*128 + 64);
    g1f[448 + tid] = fmaxf(acc + b2[tid], 0.f);
  }
  __syncthreads();

  if (tid < 64) {
    float v = g1f[448 + lane] * w3[lane];
    v = wred64(v);
    if (lane == 0) out[b] = v + b3[0];
  }
}

extern "C" void kernel_launch(void* const* d_in, const int* in_sizes, int n_in,
                              void* d_out, int out_size, void* d_ws, size_t ws_size,
                              hipStream_t stream) {
  (void)n_in; (void)ws_size; (void)out_size;
  const float* dense_x = (const float*)d_in[0];
  const float* dense_W = (const float*)d_in[1];
  const float* dense_b = (const float*)d_in[2];
  const float* tbl     = (const float*)d_in[3];
  const float* cls     = (const float*)d_in[4];
  const float* ng      = (const float*)d_in[5];
  const float* nb      = (const float*)d_in[6];
  const float* xW      = (const float*)d_in[7];
  const float* xb      = (const float*)d_in[8];
  const float* Ap      = (const float*)d_in[9];
  const float* Dp      = (const float*)d_in[10];
  const float* oW      = (const float*)d_in[11];
  const float* ob      = (const float*)d_in[12];
  const float* mW      = (const float*)d_in[13];
  const float* mb      = (const float*)d_in[14];
  const float* aiW     = (const float*)d_in[15];
  const float* aib     = (const float*)d_in[16];
  const float* aoW     = (const float*)d_in[17];
  const float* aob     = (const float*)d_in[18];
  const float* w1      = (const float*)d_in[19];
  const float* b1      = (const float*)d_in[20];
  const float* w2      = (const float*)d_in[21];
  const float* b2      = (const float*)d_in[22];
  const float* w3      = (const float*)d_in[23];
  const float* b3      = (const float*)d_in[24];
  const int*   sidx    = (const int*)d_in[25];
  float* out = (float*)d_out;
  unsigned short* wsb = (unsigned short*)d_ws;

  hipLaunchKernelGGL(prep_kernel, dim3(256), dim3(256), 0, stream,
                     xW, oW, ob, mW, mb, aiW, Ap, wsb);

  const int B = in_sizes[0] / 13;  // 1024
  hipLaunchKernelGGL(Mamba4CTRV19_kernel, dim3(B), dim3(256), 0, stream,
                     dense_x, dense_W, dense_b, tbl, cls, ng, nb, xb, Dp, ob, mb,
                     aib, aoW, aob, w1, b1, w2, b2, w3, b3, sidx, wsb, out);
}